// Round 13
// baseline (611.347 us; speedup 1.0000x reference)
//
#include <hip/hip_runtime.h>

typedef _Float16 half8 __attribute__((ext_vector_type(8)));
typedef _Float16 half4 __attribute__((ext_vector_type(4)));
typedef __fp16   pk2   __attribute__((ext_vector_type(2)));
typedef float    f32x4 __attribute__((ext_vector_type(4)));

#define GLOBAL_AS __attribute__((address_space(1)))
#define LDS_AS    __attribute__((address_space(3)))

static constexpr int Bb = 32;
static constexpr int Nn = 2048;
static constexpr int Dd = 1024;
static constexpr int M  = Bb * Nn;   // 65536 rows of the big GEMM

// ---------------------------------------------------------------------------
// PERSISTENT-ET: grid 256 (1 block/CU), each block = one mtile x ALL 4 et
// tiles as ONE continuous 64-tile pipeline (loop body byte-identical to the
// proven r7/r12 schedule). A-chunk = t&15 (slab re-read via L3); B-chunk = t
// (linear in W1TT) -> staging cadence never breaks. Per-et epilogue uses a
// DEDICATED 4 KB usum region (LDS 132 KB) + raw BAR/LGKM (no __syncthreads,
// which would vmcnt(0)-drain the prefetch). Saves 3x prologue/drain per CU
// + the 4-deep block-wave tail of the 1024-block grid.
//
// B layout (prep0 -> gemm8): chunk = 128 cols x 64 k f16 = 16 KB, staged
// linearly by global_load_lds; unit u = q*128 + s holds col s ^ (2*(q&3)).
// W1TT chunks: [et(4)][t(16)][h(2)] = linear in t = et*16+T.
// A: f32 from `encoded`, reg-staged (8 dwordx4 -> cvt_pkrtz -> 8 ds_write_b64)
// into a row-major swizzled image: half4 unit (row,kc) at row*16 +
// (kc ^ (2*(row&7))). Write conflict-free (measured 0), read 2-way (free).
// ---------------------------------------------------------------------------

// Kernel 1: fused prep -- blocks 0-511 pack W1, blocks 512-1023 compute dec.
__global__ void prep0(const float* __restrict__ W1, _Float16* __restrict__ W1TT,
                      const float* __restrict__ ds, const float* __restrict__ W2,
                      float* __restrict__ dec) {
    const int id = blockIdx.x;
    const int tid = threadIdx.x;
    if (id < 512) {
        int g = id * 256 + tid;                   // 131072 half8 units
        int chunk = g >> 10;                      // et*32 + t*2 + h
        int u = g & 1023;
        int q = u >> 7, sc = u & 127;
        int cl = sc ^ (2 * (q & 3));
        int et = chunk >> 5, t = (chunk >> 1) & 15, h = chunk & 1;
        int e  = et * 256 + h * 128 + cl;
        int k0 = t * 64 + q * 8;
        half8 hh;
#pragma unroll
        for (int j = 0; j < 8; ++j)
            hh[j] = (_Float16)W1[(size_t)(k0 + j) * Dd + e];
        *(half8*)(W1TT + (size_t)g * 8) = hh;
    } else {
        __shared__ float part[4][64];
        const int id2 = id - 512;
        const int b = id2 >> 4, ech = id2 & 15;
        int e = ech * 64 + (tid & 63);
        int dc = tid >> 6;
        float acc = 0.f;
#pragma unroll 4
        for (int d = dc * 256; d < dc * 256 + 256; ++d)
            acc += ds[b * Dd + d] * W2[(size_t)d * Dd + e];
        part[dc][tid & 63] = acc;
        __syncthreads();
        if (tid < 64)
            dec[b * Dd + e] = part[0][tid] + part[1][tid]
                            + part[2][tid] + part[3][tid];
    }
}

// ---------------------------------------------------------------------------
// Kernel 2: 256x256 tile, 8 waves, fused f32->f16 A-staging, persistent-et.
// Per tile t (0..63): issue 8 A dwordx4 + 4 B global_load_lds for t+1;
// ds_read + counted-lgkm quadrant overlap (q1: LGKM(4), q2: LGKM(0));
// RD_A h1; LGKM(0); q3 q4; VM(4) -> writeA(t+1); VM(0); LGKM(0); BAR.
// At (t&15)==15: per-et epilogue (dedicated usum region, raw barriers,
// over-drain VM(0) after its 8 vtv/dcv loads -- counted gates are "<=N" so
// over-draining is always safe), zero acc, pipeline continues.
// ---------------------------------------------------------------------------
#define BAR     asm volatile("s_barrier" ::: "memory")
#define LGKM(n) asm volatile("s_waitcnt lgkmcnt(" #n ")" ::: "memory")
#define VM(n)   asm volatile("s_waitcnt vmcnt(" #n ")" ::: "memory")
#define PRIO1   __builtin_amdgcn_s_setprio(1)
#define PRIO0   __builtin_amdgcn_s_setprio(0)

// A image: half4 unit (row,kc) -> halfword addr (row*16 + (kc ^ ((row&7)*2)))*4
#define RD_A(dst, base) do { _Pragma("unroll") \
  for (int ks = 0; ks < 2; ++ks) { \
    _Pragma("unroll") for (int m2 = 0; m2 < 4; ++m2) { \
      const int row_ = m2 * 32 + rA; \
      const int kc0_ = (ks * 4 + qq) * 2; \
      dst[m2][ks] = *(const half8*)&lds[(base) + (row_ * 16 + (kc0_ ^ rxa)) * 4]; \
    } } } while (0)

#define RD_B(dst, base) do { _Pragma("unroll") \
  for (int ks = 0; ks < 2; ++ks) { const int qb = ((ks * 4 + qq) * 128) * 8; \
    _Pragma("unroll") for (int j2 = 0; j2 < 2; ++j2) \
      dst[j2][ks] = *(const half8*)&lds[(base) + qb + (j2 * 64 + rB) * 8]; } } while (0)

#define MFMAQ(A_, B_, ro, co) do { \
  _Pragma("unroll") for (int m2 = 0; m2 < 4; ++m2) \
  _Pragma("unroll") for (int j2 = 0; j2 < 2; ++j2) { \
    acc[(ro) + m2][(co) + j2] = __builtin_amdgcn_mfma_f32_16x16x32_f16( \
        A_[m2][0], B_[j2][0], acc[(ro) + m2][(co) + j2], 0, 0, 0); \
    acc[(ro) + m2][(co) + j2] = __builtin_amdgcn_mfma_f32_16x16x32_f16( \
        A_[m2][1], B_[j2][1], acc[(ro) + m2][(co) + j2], 0, 0, 0); } } while (0)

__global__ __launch_bounds__(512, 2) void gemm8(
    const float* __restrict__ encA, const _Float16* __restrict__ W1TT,
    const float* __restrict__ dec, const float* __restrict__ vt,
    float* __restrict__ u_part)          // [4][65536]
{
    extern __shared__ _Float16 lds[];    // 65536 staging halfs + 4 KB usum

    const int g  = blockIdx.x;                   // 0..255
    const int mtile = (g & 7) * 32 + (g >> 3);   // XCD-chunked swizzle (256%8==0)

    const int tid  = threadIdx.x;
    const int lane = tid & 63, wid = tid >> 6;
    const int wr = wid >> 2, wc = wid & 3;
    const int qq = lane >> 4, l15 = lane & 15;
    const int l15s = l15 ^ (2 * qq);             // B read-side bank swizzle
    const int rA = wr * 16 + l15;                // A rows: plain (layout swizzles)
    const int rxa = (l15 & 7) * 2;               // A read XOR (row&7)*2
    const int rB = wc * 16 + l15s;

    f32x4 acc[8][4] = {};
    half8 a[4][2], b0[2][2], b1[2][2];
    f32x4 aSt[8];

    // A staging geometry: instr p covers rows p*32 + (tid>>4); lane covers
    // cols l16*4..+4 of the 64-wide K-slab (4 rows x 256 B contiguous/instr).
    const int arow0 = tid >> 4;                  // 0..31
    const int l16   = tid & 15;
    const float* agp = encA + (((size_t)(mtile * 256 + arow0)) << 10) + l16 * 4;

    const int uoff = tid * 8;                    // per-thread 16B within chunk
    float* usum = (float*)(lds + 65536);         // dedicated 4 KB region

    auto issueA = [&](int Tn) {                  // A chunk repeats every 16
        const float* gp = agp + (Tn & 15) * 64;
#pragma unroll
        for (int p = 0; p < 8; ++p)
            aSt[p] = *(const f32x4*)(gp + ((size_t)p << 15));   // p*32 rows
    };
    auto writeA = [&](int Tn) {
        const int base = (Tn & 1) << 14;         // A slot base (halfwords)
#pragma unroll
        for (int p = 0; p < 8; ++p) {
            const int rf = p * 32 + arow0;
            const int h  = rf >> 7, row = rf & 127;
            pk2 c0 = __builtin_amdgcn_cvt_pkrtz(aSt[p][0], aSt[p][1]);
            pk2 c1 = __builtin_amdgcn_cvt_pkrtz(aSt[p][2], aSt[p][3]);
            half4 hh; hh[0] = c0[0]; hh[1] = c0[1]; hh[2] = c1[0]; hh[3] = c1[1];
            *(half4*)&lds[base + h * 8192
                          + (row * 16 + (l16 ^ ((row & 7) * 2))) * 4] = hh;
        }
    };
    auto stB = [&](int Tn, int h) {              // B chunk index linear in t
        const _Float16* gp = W1TT + ((size_t)(Tn * 2 + h) << 13) + uoff;
        _Float16* lp = lds + (32768 + (((Tn & 1) * 2 + h) << 13) + (wid << 9));
        __builtin_amdgcn_global_load_lds((const GLOBAL_AS void*)gp,
                                         (LDS_AS void*)lp, 16, 0, 0);
        __builtin_amdgcn_global_load_lds((const GLOBAL_AS void*)(gp + 4096),
                                         (LDS_AS void*)(lp + 4096), 16, 0, 0);
    };

    // LDS bases (halfword units): tile slot = t&1.
    // A: slot0 h0=0, h1=8192 ; slot1 h0=16384, h1=24576.  B: +32768 each.

    // prologue: stage tile 0 (A via reg path, B via global_load_lds)
    issueA(0); stB(0, 0); stB(0, 1);
    VM(4);                                       // A8 landed (B4 outstanding)
    writeA(0);
    VM(0); LGKM(0);
    BAR;

#pragma unroll 2
    for (int t = 0; t < 64; ++t) {
        const int As  = (t & 1) << 14;           // A slot base (halfwords)
        const int Bs2 = 32768 + ((t & 1) << 14); // B slot base
        const bool s = (t < 63);

        // staging for tile t+1 first: maximizes in-flight slack
        if (s) { issueA(t + 1); stB(t + 1, 0); stB(t + 1, 1); }

        // tile t compute with counted-lgkm quadrant overlap (r7 body, exact)
        RD_A(a, As);                 // 8 ds_read_b128 (rows 0..127)
        RD_B(b0, Bs2);               // 4
        RD_B(b1, Bs2 + 8192);        // 4
        LGKM(4);                     // a + b0 resident (b1 draining)
        PRIO1; MFMAQ(a, b0, 0, 0); PRIO0;
        LGKM(0);                     // b1 resident
        PRIO1; MFMAQ(a, b1, 0, 2); PRIO0;
        RD_A(a, As + 8192);          // rows 128..255 (WAR on a: safe, q2 issued)
        LGKM(0);
        PRIO1; MFMAQ(a, b0, 4, 0); MFMAQ(a, b1, 4, 2); PRIO0;

        if (s) { VM(4); writeA(t + 1); }         // A regs landed ~2000 cyc ago
        VM(0); LGKM(0);                          // B landed; ds_writes retired
        BAR;                                     // slot t&1 free; t+1 readable

        // ---- per-et epilogue: tanh(c + dec) * vt, reduce 256 cols ---------
        if ((t & 15) == 15) {
            const int et = t >> 4;
            const int b = mtile >> 3;            // 8 mtiles per batch row
            float vtv[4], dcv[4];
#pragma unroll
            for (int nf = 0; nf < 4; ++nf) {
                int e = et * 256 + (nf >> 1) * 128 + (nf & 1) * 64 + wc * 16 + l15;
                vtv[nf] = vt[e];
                dcv[nf] = dec[b * Dd + e];
            }
            VM(0);                   // over-drain (safe: gates are "<=N");
                                     // also retires these 8 epilogue loads
#pragma unroll
            for (int hm = 0; hm < 8; ++hm) {
                const int h = hm >> 2, mq = hm & 3;
#pragma unroll
                for (int r = 0; r < 4; ++r) {
                    float sv = 0.f;
#pragma unroll
                    for (int nf = 0; nf < 4; ++nf) {
                        float x  = acc[hm][nf][r] + dcv[nf];
                        float ex = __expf(2.f * x);
                        sv += (1.f - 2.f * __builtin_amdgcn_rcpf(ex + 1.f)) * vtv[nf];
                    }
#pragma unroll
                    for (int off = 1; off < 16; off <<= 1)
                        sv += __shfl_xor(sv, off, 16);
                    if (l15 == 0)
                        usum[wc * 256 + h * 128 + mq * 32 + wr * 16 + qq * 4 + r] = sv;
                }
            }
            LGKM(0); BAR;            // raw barrier: does NOT drain vmcnt
            if (tid < 256) {
                float v = usum[tid] + usum[256 + tid]
                        + usum[512 + tid] + usum[768 + tid];
                u_part[(size_t)et * M + (size_t)mtile * 256 + tid] = v;
            }
#pragma unroll
            for (int hm = 0; hm < 8; ++hm)
#pragma unroll
                for (int nf = 0; nf < 4; ++nf)
                    acc[hm][nf] = (f32x4){0.f, 0.f, 0.f, 0.f};
        }
    }
}

// ---------------------------------------------------------------------------
// Kernel 3: masked log-softmax over N=2048 per batch row (4 partial slices).
// ---------------------------------------------------------------------------
__global__ void softmax_k(const float* __restrict__ up, const int* __restrict__ mask,
                          float* __restrict__ out) {
    __shared__ float red[8];
    int b = blockIdx.x, tid = threadIdx.x;
    float l[8];
#pragma unroll
    for (int i = 0; i < 8; ++i) {
        int n = i * 256 + tid;
        float s = up[(size_t)b * Nn + n];
#pragma unroll
        for (int et = 1; et < 4; ++et) s += up[(size_t)et * M + (size_t)b * Nn + n];
        l[i] = s + (mask[b * Nn + n] ? 0.f : -103.278931f);  // ln(2^-149)
    }
    float m = l[0];
#pragma unroll
    for (int i = 1; i < 8; ++i) m = fmaxf(m, l[i]);
#pragma unroll
    for (int o = 32; o >= 1; o >>= 1) m = fmaxf(m, __shfl_xor(m, o, 64));
    if ((tid & 63) == 0) red[tid >> 6] = m;
    __syncthreads();
    m = fmaxf(fmaxf(red[0], red[1]), fmaxf(red[2], red[3]));
    float s = 0.f;
#pragma unroll
    for (int i = 0; i < 8; ++i) s += expf(l[i] - m);
#pragma unroll
    for (int o = 32; o >= 1; o >>= 1) s += __shfl_xor(s, o, 64);
    if ((tid & 63) == 0) red[4 + (tid >> 6)] = s;
    __syncthreads();
    float lse = m + logf(red[4] + red[5] + red[6] + red[7]);
#pragma unroll
    for (int i = 0; i < 8; ++i)
        out[(size_t)b * Nn + i * 256 + tid] = l[i] - lse;
}

// ---------------------------------------------------------------------------
extern "C" void kernel_launch(void* const* d_in, const int* in_sizes, int n_in,
                              void* d_out, int out_size, void* d_ws, size_t ws_size,
                              hipStream_t stream) {
    const float* encoded = (const float*)d_in[0];
    const float* dstate  = (const float*)d_in[1];
    const int*   mask    = (const int*)d_in[2];
    const float* W1      = (const float*)d_in[3];
    const float* W2      = (const float*)d_in[4];
    const float* vt      = (const float*)d_in[5];
    float* out = (float*)d_out;

    // ws layout: u_part (1 MiB) | dec (128 KB) | W1TT (2 MiB)   (~3.2 MB)
    char* ws = (char*)d_ws;
    float*    u_part = (float*)ws;
    float*    dec    = (float*)(ws + (size_t)4 * M * 4);
    _Float16* W1TT   = (_Float16*)(ws + (size_t)4 * M * 4 + (size_t)Bb * Dd * 4);

    static bool attr_done = false;
    if (!attr_done) {
        hipFuncSetAttribute(reinterpret_cast<const void*>(gemm8),
                            hipFuncAttributeMaxDynamicSharedMemorySize, 135168);
        attr_done = true;
    }

    prep0<<<1024, 256, 0, stream>>>(W1, W1TT, dstate, W2, dec);
    gemm8<<<256, 512, 135168, stream>>>(encoded, W1TT, dec, vt, u_part);
    softmax_k<<<32, 256, 0, stream>>>(u_part, mask, out);
}